// Round 10
// baseline (415.186 us; speedup 1.0000x reference)
//
#include <hip/hip_runtime.h>
#include <hip/hip_bf16.h>

typedef float f32x4 __attribute__((ext_vector_type(4)));
typedef __bf16 bf16x8 __attribute__((ext_vector_type(8)));
typedef unsigned int u32;
typedef unsigned int u32x4 __attribute__((ext_vector_type(4)));

#if defined(__has_builtin)
#if __has_builtin(__builtin_amdgcn_exp2f)
#define EXP2F(x) __builtin_amdgcn_exp2f(x)
#else
#define EXP2F(x) exp2f(x)
#endif
#if __has_builtin(__builtin_amdgcn_rcpf)
#define RCPF(x) __builtin_amdgcn_rcpf(x)
#else
#define RCPF(x) (1.0f/(x))
#endif
#else
#define EXP2F(x) exp2f(x)
#define RCPF(x) (1.0f/(x))
#endif

#define MFMA16(a,b,c) __builtin_amdgcn_mfma_f32_16x16x32_bf16((a),(b),(c),0,0,0)

__device__ __forceinline__ unsigned short f2bf(float f) {
  return __builtin_bit_cast(unsigned short, (__bf16)f);
}

// pack two f32 -> one u32 of 2 bf16 (RNE), lo = a, hi = b
__device__ __forceinline__ u32 pkbf(float a, float b) {
  u32 d;
  asm("v_cvt_pk_bf16_f32 %0, %1, %2" : "=v"(d) : "v"(a), "v"(b));
  return d;
}

// d_ws layout: [0..65535] = W1Tg (pi x sigma permuted W1^T, fwd A image)
//              [65536..131071] = W1b (natural bf16 W1, bwd A image)
//   rho: jb=rho>>5, jf=(rho>>4)&1, a=(rho>>2)&3, c=rho&3  -> j = jb*32 + a*8 + jf*4 + c   [pi]
//   iota: kb=io>>5,  u=(io>>3)&3,  v=io&7                 -> i = kb*32 + (v>>2)*16 + u*4 + (v&3)  [sigma]
__global__ __launch_bounds__(256) void hn_prep(const float* __restrict__ W1,
                                               unsigned short* __restrict__ ws) {
  int t = blockIdx.x * 256 + threadIdx.x;  // 65536 threads
  int rho = t >> 7, io = t & 127;
  int j = (rho >> 5) * 32 + ((rho >> 2) & 3) * 8 + ((rho >> 4) & 1) * 4 + (rho & 3);
  int i = (io >> 5) * 32 + ((io >> 2) & 1) * 16 + ((io >> 3) & 3) * 4 + (io & 3);
  ws[t] = f2bf(W1[i * 512 + j]);          // W1Tg[rho][io]
  ws[65536 + t] = f2bf(W1[t]);            // W1b natural [i][j]
}

// One block = 256 batch rows (8 waves x 32 rows), 256 blocks, 2 waves/SIMD.
// f32 q master (precision: R9 lesson). No gacc array: bwd partials fold into
// p per-jblk (R6-verified reassociation) -> registers freed for the software
// pipeline fwd(j) || bwd(j-1), with qbw hoisted per step.
__global__ __launch_bounds__(512, 2) void hn_main(
    const float* __restrict__ x, const float* __restrict__ W1,
    const float* __restrict__ b1, const float* __restrict__ W2,
    const unsigned short* __restrict__ wsp, float* __restrict__ out) {
  __shared__ __align__(16) char w1f[131072];  // W1Tg bf16 [512 rho][128 io], ^((rho&7)<<4)
  __shared__ __align__(16) float b1s[512];    // b1 * 2*log2(e)
  __shared__ __align__(16) float w2s[512];

  const int tid = threadIdx.x;
  const int lane = tid & 63;
  const int w = tid >> 6;      // 0..7
  const int m = lane & 15;
  const int g = lane >> 4;

  // ---- stage W1Tg -> LDS (linear copy + row-XOR swizzle; XOR only, no carries)
  for (int it = tid; it < 8192; it += 512) {
    int flat = it << 3;                      // element index = rho*128 + io, 8 at a time
    int rho = flat >> 7;
    u32x4 v = *(const u32x4*)(wsp + flat);   // 16B = 8 bf16
    int ba = flat << 1;
    *(u32x4*)(w1f + (ba ^ ((rho & 7) << 4))) = v;
  }
  if (tid < 512) {
    b1s[tid] = b1[tid] * 2.8853900817779268f;
    w2s[tid] = W2[tid];
  }
  __syncthreads();

  const int b0 = blockIdx.x * 256 + w * 32;

  // q/p f32 masters in sigma layout:
  // element r of frag = (row b0+16bf+m, i = 32kb + 16*(r>>2) + 4g + (r&3))
  float q[2][4][8], p[2][4][8];
#pragma unroll
  for (int bf = 0; bf < 2; ++bf)
#pragma unroll
    for (int kb = 0; kb < 4; ++kb) {
      const float* r0 = x + (long)(b0 + 16 * bf + m) * 256 + kb * 32 + g * 4;
#pragma unroll
      for (int h = 0; h < 2; ++h) {
        f32x4 qv = *(const f32x4*)(r0 + h * 16);
        f32x4 pv = *(const f32x4*)(r0 + h * 16 + 128);
#pragma unroll
        for (int rr = 0; rr < 4; ++rr) {
          q[bf][kb][4 * h + rr] = qv[rr];
          p[bf][kb][4 * h + rr] = pv[rr];
        }
      }
    }

  // lane-constant bases. Swizzle XOR applied to FULL low-bit address (no carries).
  const int sw = (m & 7) << 4;
  const int lbF[4] = {
      (m * 256 + 0 * 64 + g * 16) ^ sw,
      (m * 256 + 1 * 64 + g * 16) ^ sw,
      (m * 256 + 2 * 64 + g * 16) ^ sw,
      (m * 256 + 3 * 64 + g * 16) ^ sw};
  const unsigned short* W1b = wsp + 65536;
  const char* bptr = (const char*)W1b + m * 1024 + g * 16;  // bwd A row m+16nf, j-chunk

  u32x4 qbw[2][4];  // bf16 image of q_old, refreshed once per step

  // fwd(jblk): z = W1Tg-tile * qbw; act -> packed s (bwd B-frag order)
  auto fwd_act = [&](int jblk, u32x4& so0, u32x4& so1) {
    f32x4 z[2][2];
    z[0][0] = f32x4{0.f,0.f,0.f,0.f}; z[0][1] = f32x4{0.f,0.f,0.f,0.f};
    z[1][0] = f32x4{0.f,0.f,0.f,0.f}; z[1][1] = f32x4{0.f,0.f,0.f,0.f};
#pragma unroll
    for (int kb = 0; kb < 4; ++kb) {
      bf16x8 qb0 = __builtin_bit_cast(bf16x8, qbw[0][kb]);
      bf16x8 qb1 = __builtin_bit_cast(bf16x8, qbw[1][kb]);
      bf16x8 a0 = *(const bf16x8*)(w1f + lbF[kb] + jblk * 8192);
      bf16x8 a1 = *(const bf16x8*)(w1f + lbF[kb] + jblk * 8192 + 4096);
      z[0][0] = MFMA16(a0, qb0, z[0][0]);
      z[0][1] = MFMA16(a0, qb1, z[0][1]);
      z[1][0] = MFMA16(a1, qb0, z[1][0]);
      z[1][1] = MFMA16(a1, qb1, z[1][1]);
    }
    // act: s = W2[j]*sech^2(z+b1[j]); C-row (jf,rr) <-> j = 32jblk+8g+4jf+rr
#pragma unroll
    for (int jf = 0; jf < 2; ++jf) {
      f32x4 b1v = *(const f32x4*)(b1s + jblk * 32 + g * 8 + jf * 4);
      f32x4 w2v = *(const f32x4*)(w2s + jblk * 32 + g * 8 + jf * 4);
#pragma unroll
      for (int bf = 0; bf < 2; ++bf) {
        const f32x4 zv = z[jf][bf];
        float sv[4];
#pragma unroll
        for (int rr = 0; rr < 4; ++rr) {
          float zz = fmaf(zv[rr], 2.8853900817779268f, b1v[rr]);
          float e = EXP2F(zz);                 // e^(2(z+b1))
          float u = RCPF(e + 1.f);
          float th = fmaf(-2.f, u, 1.f);       // tanh
          sv[rr] = fmaf(-th * th, w2v[rr], w2v[rr]);
        }
        u32 w0 = pkbf(sv[0], sv[1]);
        u32 w1p = pkbf(sv[2], sv[3]);
        if (bf == 0) { so0[jf * 2] = w0; so0[jf * 2 + 1] = w1p; }
        else         { so1[jf * 2] = w0; so1[jf * 2 + 1] = w1p; }
      }
    }
  };

  // bwd(jblk): partial g tiles folded straight into p (R6-verified mapping:
  // gt[nf] row i=16nf+4g+rr, col b=m+16bf  ==  p[bf][nf>>1][(nf&1)*4+rr])
  auto bwd_fold = [&](int jblk, u32x4 s0, u32x4 s1) {
    bf16x8 sB0 = __builtin_bit_cast(bf16x8, s0);
    bf16x8 sB1 = __builtin_bit_cast(bf16x8, s1);
    const f32x4 zc = f32x4{0.f, 0.f, 0.f, 0.f};
#pragma unroll
    for (int nf = 0; nf < 8; ++nf) {
      bf16x8 af = *(const bf16x8*)(bptr + nf * 16384 + jblk * 64);
      f32x4 gt0 = MFMA16(af, sB0, zc);
      f32x4 gt1 = MFMA16(af, sB1, zc);
      const int kb = nf >> 1, h4 = (nf & 1) * 4;
#pragma unroll
      for (int rr = 0; rr < 4; ++rr) {
        p[0][kb][h4 + rr] = fmaf(-0.1f, gt0[rr], p[0][kb][h4 + rr]);
        p[1][kb][h4 + rr] = fmaf(-0.1f, gt1[rr], p[1][kb][h4 + rr]);
      }
    }
  };

#pragma unroll 1
  for (int step = 0; step < 10; ++step) {
    // snapshot q_old as bf16, then advance q with p_old (leapfrog: both use olds)
#pragma unroll
    for (int bf = 0; bf < 2; ++bf)
#pragma unroll
      for (int kb = 0; kb < 4; ++kb)
#pragma unroll
        for (int h = 0; h < 4; ++h)
          qbw[bf][kb][h] = pkbf(q[bf][kb][2 * h], q[bf][kb][2 * h + 1]);

#pragma unroll
    for (int bf = 0; bf < 2; ++bf)
#pragma unroll
      for (int kb = 0; kb < 4; ++kb)
#pragma unroll
        for (int r = 0; r < 8; ++r)
          q[bf][kb][r] = fmaf(0.1f, p[bf][kb][r], q[bf][kb][r]);

    // software pipeline: bwd(j-1) [L2 loads + MFMA, independent] overlaps
    // fwd(j)+act(j) [LDS + MFMA + VALU]
    u32x4 sA0, sA1, sC0, sC1;
    fwd_act(0, sA0, sA1);
#pragma unroll 1
    for (int jblk = 1; jblk < 16; ++jblk) {
      fwd_act(jblk, sC0, sC1);
      bwd_fold(jblk - 1, sA0, sA1);
      sA0 = sC0; sA1 = sC1;
    }
    bwd_fold(15, sA0, sA1);
  }

  // ---- store concat(q, p) with the same sigma addressing
#pragma unroll
  for (int bf = 0; bf < 2; ++bf)
#pragma unroll
    for (int kb = 0; kb < 4; ++kb) {
      float* o = out + (long)(b0 + 16 * bf + m) * 256 + kb * 32 + g * 4;
#pragma unroll
      for (int h = 0; h < 2; ++h) {
        f32x4 qv, pv;
#pragma unroll
        for (int rr = 0; rr < 4; ++rr) {
          qv[rr] = q[bf][kb][4 * h + rr];
          pv[rr] = p[bf][kb][4 * h + rr];
        }
        *(f32x4*)(o + h * 16) = qv;
        *(f32x4*)(o + h * 16 + 128) = pv;
      }
    }
}

extern "C" void kernel_launch(void* const* d_in, const int* in_sizes, int n_in,
                              void* d_out, int out_size, void* d_ws, size_t ws_size,
                              hipStream_t stream) {
  const float* x  = (const float*)d_in[0];
  const float* W1 = (const float*)d_in[1];
  const float* b1 = (const float*)d_in[2];
  const float* W2 = (const float*)d_in[3];
  // d_in[4] = b2: affects only V's value, not its gradient -> unused.
  float* out = (float*)d_out;
  unsigned short* wsp = (unsigned short*)d_ws;  // 256 KB: W1Tg + W1b

  hipLaunchKernelGGL(hn_prep, dim3(256), dim3(256), 0, stream, W1, wsp);
  hipLaunchKernelGGL(hn_main, dim3(256), dim3(512), 0, stream,
                     x, W1, b1, W2, wsp, out);
}